// Round 8
// baseline (1101.016 us; speedup 1.0000x reference)
//
#include <hip/hip_runtime.h>
#include <hip/hip_bf16.h>

typedef short short8 __attribute__((ext_vector_type(8)));
typedef float f32x4 __attribute__((ext_vector_type(4)));

#define DEV __device__ __forceinline__
#define AS1 __attribute__((address_space(1)))
#define AS3 __attribute__((address_space(3)))

// ---------------------------------------------------------------- async 16B global->LDS (GEMM)
DEV void async_load16(const void* g, void* l) {
    __builtin_amdgcn_global_load_lds((const AS1 unsigned int*)g, (AS3 unsigned int*)l, 16, 0, 0);
}

// ---------------------------------------------------------------- DPP 16-lane sum butterfly
template <int CTRL>
DEV float dpp_add16(float v) {
    int t = __builtin_amdgcn_update_dpp(0, __float_as_int(v), CTRL, 0xf, 0xf, true);
    return v + __int_as_float(t);
}
DEV float row_sum16(float v) {
    v = dpp_add16<0x128>(v);  // row_ror:8
    v = dpp_add16<0x124>(v);  // row_ror:4
    v = dpp_add16<0x122>(v);  // row_ror:2
    v = dpp_add16<0x121>(v);  // row_ror:1
    return v;
}

// ---------------------------------------------------------------- f32 -> bf16 cast
__global__ __launch_bounds__(256) void cast_bf16_kernel(const float* __restrict__ in,
                                                        __hip_bfloat16* __restrict__ out, int n) {
    int i = (blockIdx.x * 256 + threadIdx.x) * 4;
    if (i < n) {
        float4 v = *(const float4*)&in[i];
        out[i + 0] = __float2bfloat16(v.x);
        out[i + 1] = __float2bfloat16(v.y);
        out[i + 2] = __float2bfloat16(v.z);
        out[i + 3] = __float2bfloat16(v.w);
    }
}

// ---------------------------------------------------------------- bf16 MFMA GEMM, C = A(M,K) * B(N,K)^T
// XCD-aware block swizzle (T1): nwg=512 divisible by 8; 64 consecutive per XCD share B-panel.
template <int EPI>
__global__ __launch_bounds__(256) void gemm_nt(const short* __restrict__ A,
                                               const short* __restrict__ Bm,
                                               float* __restrict__ C,
                                               const float* __restrict__ bias,
                                               int M, int N, int K) {
    __shared__ short lda[128 * 32];
    __shared__ short ldb[128 * 32];
    const int tid  = threadIdx.x;
    const int lane = tid & 63;
    const int wave = tid >> 6;

    const int nbx = M >> 7;  // 32
    const int wg  = blockIdx.y * gridDim.x + blockIdx.x;
    const int nwg = gridDim.x * gridDim.y;
    const int cpx = nwg >> 3;
    const int swz = (wg & 7) * cpx + (wg >> 3);
    const int m0 = (swz & (nbx - 1)) * 128;
    const int n0 = (swz / nbx) * 128;

    const int wm = (wave >> 1) * 64;
    const int wn = (wave & 1) * 64;
    f32x4 acc[4][4] = {};

    const int sr = tid >> 2;
    const int sc = (tid & 3) * 8;
    const short* Ab  = A  + (size_t)(m0 + sr) * K + sc;
    const short* Ab2 = Ab + (size_t)64 * K;
    const short* Bb  = Bm + (size_t)(n0 + sr) * K + sc;
    const short* Bb2 = Bb + (size_t)64 * K;
    short* la  = &lda[tid * 8];
    short* la2 = &lda[(tid + 256) * 8];
    short* lb  = &ldb[tid * 8];
    short* lb2 = &ldb[(tid + 256) * 8];

    const int fk = (lane >> 4) * 8;
    const int fr = lane & 15;

    for (int k0 = 0; k0 < K; k0 += 32) {
        async_load16(Ab + k0,  la);
        async_load16(Ab2 + k0, la2);
        async_load16(Bb + k0,  lb);
        async_load16(Bb2 + k0, lb2);
        __syncthreads();
        short8 af[4], bfr[4];
#pragma unroll
        for (int i = 0; i < 4; i++) af[i]  = *(const short8*)&lda[(wm + i * 16 + fr) * 32 + fk];
#pragma unroll
        for (int j = 0; j < 4; j++) bfr[j] = *(const short8*)&ldb[(wn + j * 16 + fr) * 32 + fk];
#pragma unroll
        for (int i = 0; i < 4; i++)
#pragma unroll
            for (int j = 0; j < 4; j++)
                acc[i][j] = __builtin_amdgcn_mfma_f32_16x16x32_bf16(af[i], bfr[j], acc[i][j], 0, 0, 0);
        __syncthreads();
    }

    const int er = (lane >> 4) * 4;
    const int ec = lane & 15;
#pragma unroll
    for (int i = 0; i < 4; i++) {
        const int gr = m0 + wm + i * 16 + er;
#pragma unroll
        for (int j = 0; j < 4; j++) {
            const int gc = n0 + wn + j * 16 + ec;
            float bia = 0.f;
            if constexpr (EPI == 1) bia = bias[gc];
#pragma unroll
            for (int r = 0; r < 4; r++) {
                float v = acc[i][j][r];
                if constexpr (EPI == 1) v = 1.f / (1.f + __expf(-(v + bia)));
                C[(size_t)(gr + r) * N + gc] = v;
            }
        }
    }
}

// ---------------------------------------------------------------- l2norm over rows of 128 (in-place)
__global__ __launch_bounds__(256) void l2norm_kernel(float* __restrict__ buf) {
    const int row  = blockIdx.x * 4 + (threadIdx.x >> 6);
    const int lane = threadIdx.x & 63;
    float* p = &buf[(size_t)row * 128 + lane * 2];
    float2 v = *(float2*)p;
    float s = v.x * v.x + v.y * v.y;
#pragma unroll
    for (int off = 1; off < 64; off <<= 1) s += __shfl_xor(s, off);
    const float inv = 1.f / fmaxf(sqrtf(s), 1e-12f);
    v.x *= inv; v.y *= inv;
    *(float2*)p = v;
}

// ---------------------------------------------------------------- beta = sigmoid(x @ Wb^T + bb), f32 exact
__global__ __launch_bounds__(256) void beta_kernel(const float* __restrict__ x,
                                                   const float* __restrict__ Wb,
                                                   const float* __restrict__ bb,
                                                   float* __restrict__ beta) {
    __shared__ float xs[16 * 132];
    const int tid = threadIdx.x;
    const float* xr = &x[(size_t)blockIdx.x * 2048];
#pragma unroll
    for (int i = tid; i < 512; i += 256) {
        float4 v = ((const float4*)xr)[i];
        const int j = i * 4;
        *(float4*)&xs[(j >> 7) * 132 + (j & 127)] = v;
    }
    __syncthreads();
    const int n = tid >> 4, ks = tid & 15;
    const float* w  = &Wb[(size_t)n * 2048 + ks * 128];
    const float* xx = &xs[ks * 132];
    float s = 0.f;
#pragma unroll 8
    for (int j = 0; j < 128; j++) s += xx[j] * w[j];
    s += __shfl_xor(s, 1); s += __shfl_xor(s, 2);
    s += __shfl_xor(s, 4); s += __shfl_xor(s, 8);
    if (ks == 0) beta[(size_t)blockIdx.x * 16 + n] = 1.f / (1.f + __expf(-(s + bb[n])));
}

// ---------------------------------------------------------------- sequential recurrence
// 128 blocks x 512 thr (8 waves) -> 1 block/CU on 128 CUs, 2 waves/SIMD (TLP hides
// the serial chain). Wave = 4 rows x 16 lanes, 8 state f32/lane. bh = blockIdx&31;
// blocks {bh,+32,+64,+96} all land on XCD bh%8 (L2-local streams, L1-shared k/q).
// 8-deep asm-volatile register rotation, ISSUE(t+7) at top of body (set consumed at
// t-1; no WAR), counted s_waitcnt vmcnt(56) + sched_barrier(0). Loads carry no
// "memory" clobber so VALU interleaves with load issue. No stores in loop: LDS ring,
// flushed every 64 steps (store absorbed by the counted wait).
__global__ __launch_bounds__(512, 2) void recurrence_kernel(
        const float* __restrict__ S0, const float* __restrict__ qn, const float* __restrict__ kn,
        const float* __restrict__ vv, const float* __restrict__ adec, const float* __restrict__ bet,
        const float* __restrict__ gg, __hip_bfloat16* __restrict__ o) {
    __shared__ __hip_bfloat16 lout[8][64][4];

    const int bh = blockIdx.x & 31;    // XCD = bh % 8
    const int rb = blockIdx.x >> 5;    // 0..3
    const int b = bh >> 4, h = bh & 15;
    const int lane = threadIdx.x & 63;
    const int wave = threadIdx.x >> 6; // 0..7
    const int r = lane >> 4;           // row within wave (0..3)
    const int c = lane & 15;           // col chunk (8 f32)
    const int i0 = rb * 32 + wave * 4;
    const int i = i0 + r;

    f32x4 S40, S41;
    {
        const float* s0 = &S0[((size_t)(bh * 128 + i)) * 128 + c * 8];
        S40 = *(const f32x4*)s0;
        S41 = *(const f32x4*)(s0 + 4);
    }

    const size_t hb = (size_t)(b * 2048) * 16 + h;
    const unsigned SB = 16 * 128 * 4;  // 8192 B per t-step
    const float* kbase = kn   + hb * 128;
    const float* qbase = qn   + hb * 128;
    const float* vbase = vv   + hb * 128;
    const float* abase = adec + hb * 128;
    const float* gbase = gg   + hb * 128;
    const float* bbase = bet  + hb;
    char* ob = (char*)(o + hb * 128 + i0);

    unsigned voff_kq = (unsigned)(c * 32);
    unsigned voff_i  = (unsigned)(i * 4);
    unsigned voff_b  = 0;

    f32x4 kA0, kA1, qA0, qA1; float vA, aA, gA, bA;
    f32x4 kB0, kB1, qB0, qB1; float vB, aB, gB, bB;
    f32x4 kC0, kC1, qC0, qC1; float vC, aC, gC, bC;
    f32x4 kD0, kD1, qD0, qD1; float vD, aD, gD, bD;
    f32x4 kE0, kE1, qE0, qE1; float vE, aE, gE, bE;
    f32x4 kF0, kF1, qF0, qF1; float vF, aF, gF, bF;
    f32x4 kG0, kG1, qG0, qG1; float vG, aG, gG, bG;
    f32x4 kH0, kH1, qH0, qH1; float vH, aH, gH, bH;

#define ISSUE(SET)                                                              \
    asm volatile("global_load_dwordx4 %0, %2, %3\n\t"                           \
                 "global_load_dwordx4 %1, %2, %3 offset:16"                     \
                 : "=v"(k##SET##0), "=v"(k##SET##1)                             \
                 : "v"(voff_kq), "s"(kbase));                                   \
    asm volatile("global_load_dwordx4 %0, %2, %3\n\t"                           \
                 "global_load_dwordx4 %1, %2, %3 offset:16"                     \
                 : "=v"(q##SET##0), "=v"(q##SET##1)                             \
                 : "v"(voff_kq), "s"(qbase));                                   \
    asm volatile("global_load_dword %0, %1, %2"                                 \
                 : "=v"(v##SET) : "v"(voff_i), "s"(vbase));                     \
    asm volatile("global_load_dword %0, %1, %2"                                 \
                 : "=v"(a##SET) : "v"(voff_i), "s"(abase));                     \
    asm volatile("global_load_dword %0, %1, %2"                                 \
                 : "=v"(g##SET) : "v"(voff_i), "s"(gbase));                     \
    asm volatile("global_load_dword %0, %1, %2"                                 \
                 : "=v"(b##SET) : "v"(voff_b), "s"(bbase));

#define ADV() { voff_kq += SB; voff_i += SB; voff_b += 64; }

    // prologue: issue steps 0..6 into A..G
    ISSUE(A); ADV();
    ISSUE(B); ADV();
    ISSUE(C); ADV();
    ISSUE(D); ADV();
    ISSUE(E); ADV();
    ISSUE(F); ADV();
    ISSUE(G); ADV();

// issue L(t+7) into PRE (consumed at t-1), wait t's loads (56 newer outstanding),
// compute t from CUR, buffer output in per-wave LDS ring.
#define BODY(SLOT, CUR, PRE)                                              \
    {                                                                     \
        ISSUE(PRE);                                                       \
        ADV();                                                            \
        asm volatile("s_waitcnt vmcnt(56)" ::: "memory");                 \
        __builtin_amdgcn_sched_barrier(0);                                \
        f32x4 ps = S40 * k##CUR##0;                                       \
        ps = S41 * k##CUR##1 + ps;                                        \
        float p = row_sum16((ps[0] + ps[1]) + (ps[2] + ps[3]));           \
        const float coef = b##CUR * (v##CUR - p);                         \
        S40 = a##CUR * S40 + coef * k##CUR##0;                            \
        S41 = a##CUR * S41 + coef * k##CUR##1;                            \
        f32x4 os = S40 * q##CUR##0;                                       \
        os = S41 * q##CUR##1 + os;                                        \
        float ov = row_sum16((os[0] + os[1]) + (os[2] + os[3]));          \
        if (c == 0) lout[wave][(SLOT)][r] = __float2bfloat16(ov * g##CUR);\
    }

    for (int tb = 0; tb < 2048; tb += 64) {
        for (int tt = 0; tt < 64; tt += 8) {
            BODY(tt,     A, H);
            BODY(tt + 1, B, A);
            BODY(tt + 2, C, B);
            BODY(tt + 3, D, C);
            BODY(tt + 4, E, D);
            BODY(tt + 5, F, E);
            BODY(tt + 6, G, F);
            BODY(tt + 7, H, G);
        }
        // flush 64 outputs: lane l -> step tb+l, 4 rows (8B); store absorbed by
        // the counted vmcnt wait (it is older than subsequent prefetch loads).
        uint2 pk = *(const uint2*)&lout[wave][lane][0];
        *(uint2*)(ob + (size_t)(tb + lane) * 4096) = pk;
    }
#undef BODY
#undef ADV
#undef ISSUE
}

// ----------------------------------------------------------------
extern "C" void kernel_launch(void* const* d_in, const int* in_sizes, int n_in,
                              void* d_out, int out_size, void* d_ws, size_t ws_size,
                              hipStream_t stream) {
    const float* x  = (const float*)d_in[0];
    const float* S0 = (const float*)d_in[1];
    const float* Wq = (const float*)d_in[2];
    const float* Wk = (const float*)d_in[3];
    const float* Wv = (const float*)d_in[4];
    const float* Wa = (const float*)d_in[5];
    const float* ba = (const float*)d_in[6];
    const float* Wb = (const float*)d_in[7];
    const float* bb = (const float*)d_in[8];
    const float* Wg = (const float*)d_in[9];
    const float* bg = (const float*)d_in[10];
    const float* Wo = (const float*)d_in[11];
    float* out = (float*)d_out;

    const int M = 4096, N = 2048, K = 2048;
    const size_t SLACK = 8 * 16 * 128 * 4;  // 8 t-steps of prefetch slack

    size_t off = 0;
    auto alloc = [&](size_t bytes) {
        void* p = (char*)d_ws + off;
        off += (bytes + 255) & ~(size_t)255;
        return p;
    };
    short* x_bf  = (short*)alloc((size_t)M * K * 2);  // later reused as o_bf
    short* Wq_bf = (short*)alloc((size_t)N * K * 2);
    short* Wk_bf = (short*)alloc((size_t)N * K * 2);
    short* Wv_bf = (short*)alloc((size_t)N * K * 2);
    short* Wa_bf = (short*)alloc((size_t)N * K * 2);
    short* Wg_bf = (short*)alloc((size_t)N * K * 2);
    short* Wo_bf = (short*)alloc((size_t)N * K * 2);
    float* qb    = (float*)alloc((size_t)M * N * 4 + SLACK);
    float* kb    = (float*)alloc((size_t)M * N * 4 + SLACK);
    float* vb    = (float*)alloc((size_t)M * N * 4 + SLACK);
    float* ab    = (float*)alloc((size_t)M * N * 4 + SLACK);
    float* gb    = (float*)alloc((size_t)M * N * 4 + SLACK);
    float* betab = (float*)alloc((size_t)M * 16 * 4 + 32768);

    cast_bf16_kernel<<<dim3((M * K / 4 + 255) / 256), dim3(256), 0, stream>>>(x,  (__hip_bfloat16*)x_bf,  M * K);
    cast_bf16_kernel<<<dim3((N * K / 4 + 255) / 256), dim3(256), 0, stream>>>(Wq, (__hip_bfloat16*)Wq_bf, N * K);
    cast_bf16_kernel<<<dim3((N * K / 4 + 255) / 256), dim3(256), 0, stream>>>(Wk, (__hip_bfloat16*)Wk_bf, N * K);
    cast_bf16_kernel<<<dim3((N * K / 4 + 255) / 256), dim3(256), 0, stream>>>(Wv, (__hip_bfloat16*)Wv_bf, N * K);
    cast_bf16_kernel<<<dim3((N * K / 4 + 255) / 256), dim3(256), 0, stream>>>(Wa, (__hip_bfloat16*)Wa_bf, N * K);
    cast_bf16_kernel<<<dim3((N * K / 4 + 255) / 256), dim3(256), 0, stream>>>(Wg, (__hip_bfloat16*)Wg_bf, N * K);
    cast_bf16_kernel<<<dim3((N * K / 4 + 255) / 256), dim3(256), 0, stream>>>(Wo, (__hip_bfloat16*)Wo_bf, N * K);

    dim3 gdim(M / 128, N / 128), bdim(256);
    gemm_nt<0><<<gdim, bdim, 0, stream>>>(x_bf, Wq_bf, qb, nullptr, M, N, K);
    gemm_nt<0><<<gdim, bdim, 0, stream>>>(x_bf, Wk_bf, kb, nullptr, M, N, K);
    gemm_nt<0><<<gdim, bdim, 0, stream>>>(x_bf, Wv_bf, vb, nullptr, M, N, K);
    gemm_nt<1><<<gdim, bdim, 0, stream>>>(x_bf, Wa_bf, ab, ba, M, N, K);
    gemm_nt<1><<<gdim, bdim, 0, stream>>>(x_bf, Wg_bf, gb, bg, M, N, K);

    l2norm_kernel<<<dim3(M * 16 / 4), dim3(256), 0, stream>>>(qb);
    l2norm_kernel<<<dim3(M * 16 / 4), dim3(256), 0, stream>>>(kb);
    beta_kernel<<<dim3(M), dim3(256), 0, stream>>>(x, Wb, bb, betab);

    __hip_bfloat16* o_bf = (__hip_bfloat16*)x_bf;
    recurrence_kernel<<<dim3(128), dim3(512), 0, stream>>>(S0, qb, kb, vb, ab, betab, gb, o_bf);

    gemm_nt<0><<<gdim, bdim, 0, stream>>>((const short*)o_bf, Wo_bf, out, nullptr, M, N, K);
}

// Round 9
// 793.181 us; speedup vs baseline: 1.3881x; 1.3881x over previous
//
#include <hip/hip_runtime.h>
#include <hip/hip_bf16.h>

typedef short short8 __attribute__((ext_vector_type(8)));
typedef float f32x4 __attribute__((ext_vector_type(4)));

#define DEV __device__ __forceinline__
#define AS1 __attribute__((address_space(1)))
#define AS3 __attribute__((address_space(3)))

// ---------------------------------------------------------------- async 16B global->LDS (GEMM)
DEV void async_load16(const void* g, void* l) {
    __builtin_amdgcn_global_load_lds((const AS1 unsigned int*)g, (AS3 unsigned int*)l, 16, 0, 0);
}

// ---------------------------------------------------------------- DPP 16-lane sum butterfly
template <int CTRL>
DEV float dpp_add16(float v) {
    int t = __builtin_amdgcn_update_dpp(0, __float_as_int(v), CTRL, 0xf, 0xf, true);
    return v + __int_as_float(t);
}
DEV float row_sum16(float v) {
    v = dpp_add16<0x128>(v);  // row_ror:8
    v = dpp_add16<0x124>(v);  // row_ror:4
    v = dpp_add16<0x122>(v);  // row_ror:2
    v = dpp_add16<0x121>(v);  // row_ror:1
    return v;
}

// ---------------------------------------------------------------- f32 -> bf16 cast
__global__ __launch_bounds__(256) void cast_bf16_kernel(const float* __restrict__ in,
                                                        __hip_bfloat16* __restrict__ out, int n) {
    int i = (blockIdx.x * 256 + threadIdx.x) * 4;
    if (i < n) {
        float4 v = *(const float4*)&in[i];
        out[i + 0] = __float2bfloat16(v.x);
        out[i + 1] = __float2bfloat16(v.y);
        out[i + 2] = __float2bfloat16(v.z);
        out[i + 3] = __float2bfloat16(v.w);
    }
}

// ---------------------------------------------------------------- bf16 MFMA GEMM, C = A(M,K) * B(N,K)^T
// XCD-aware block swizzle (T1): nwg=512 divisible by 8.
template <int EPI>
__global__ __launch_bounds__(256) void gemm_nt(const short* __restrict__ A,
                                               const short* __restrict__ Bm,
                                               float* __restrict__ C,
                                               const float* __restrict__ bias,
                                               int M, int N, int K) {
    __shared__ short lda[128 * 32];
    __shared__ short ldb[128 * 32];
    const int tid  = threadIdx.x;
    const int lane = tid & 63;
    const int wave = tid >> 6;

    const int nbx = M >> 7;  // 32
    const int wg  = blockIdx.y * gridDim.x + blockIdx.x;
    const int nwg = gridDim.x * gridDim.y;
    const int cpx = nwg >> 3;
    const int swz = (wg & 7) * cpx + (wg >> 3);
    const int m0 = (swz & (nbx - 1)) * 128;
    const int n0 = (swz / nbx) * 128;

    const int wm = (wave >> 1) * 64;
    const int wn = (wave & 1) * 64;
    f32x4 acc[4][4] = {};

    const int sr = tid >> 2;
    const int sc = (tid & 3) * 8;
    const short* Ab  = A  + (size_t)(m0 + sr) * K + sc;
    const short* Ab2 = Ab + (size_t)64 * K;
    const short* Bb  = Bm + (size_t)(n0 + sr) * K + sc;
    const short* Bb2 = Bb + (size_t)64 * K;
    short* la  = &lda[tid * 8];
    short* la2 = &lda[(tid + 256) * 8];
    short* lb  = &ldb[tid * 8];
    short* lb2 = &ldb[(tid + 256) * 8];

    const int fk = (lane >> 4) * 8;
    const int fr = lane & 15;

    for (int k0 = 0; k0 < K; k0 += 32) {
        async_load16(Ab + k0,  la);
        async_load16(Ab2 + k0, la2);
        async_load16(Bb + k0,  lb);
        async_load16(Bb2 + k0, lb2);
        __syncthreads();
        short8 af[4], bfr[4];
#pragma unroll
        for (int i = 0; i < 4; i++) af[i]  = *(const short8*)&lda[(wm + i * 16 + fr) * 32 + fk];
#pragma unroll
        for (int j = 0; j < 4; j++) bfr[j] = *(const short8*)&ldb[(wn + j * 16 + fr) * 32 + fk];
#pragma unroll
        for (int i = 0; i < 4; i++)
#pragma unroll
            for (int j = 0; j < 4; j++)
                acc[i][j] = __builtin_amdgcn_mfma_f32_16x16x32_bf16(af[i], bfr[j], acc[i][j], 0, 0, 0);
        __syncthreads();
    }

    const int er = (lane >> 4) * 4;
    const int ec = lane & 15;
#pragma unroll
    for (int i = 0; i < 4; i++) {
        const int gr = m0 + wm + i * 16 + er;
#pragma unroll
        for (int j = 0; j < 4; j++) {
            const int gc = n0 + wn + j * 16 + ec;
            float bia = 0.f;
            if constexpr (EPI == 1) bia = bias[gc];
#pragma unroll
            for (int r = 0; r < 4; r++) {
                float v = acc[i][j][r];
                if constexpr (EPI == 1) v = 1.f / (1.f + __expf(-(v + bia)));
                C[(size_t)(gr + r) * N + gc] = v;
            }
        }
    }
}

// ---------------------------------------------------------------- l2norm over rows of 128 (in-place)
__global__ __launch_bounds__(256) void l2norm_kernel(float* __restrict__ buf) {
    const int row  = blockIdx.x * 4 + (threadIdx.x >> 6);
    const int lane = threadIdx.x & 63;
    float* p = &buf[(size_t)row * 128 + lane * 2];
    float2 v = *(float2*)p;
    float s = v.x * v.x + v.y * v.y;
#pragma unroll
    for (int off = 1; off < 64; off <<= 1) s += __shfl_xor(s, off);
    const float inv = 1.f / fmaxf(sqrtf(s), 1e-12f);
    v.x *= inv; v.y *= inv;
    *(float2*)p = v;
}

// ---------------------------------------------------------------- beta = sigmoid(x @ Wb^T + bb), f32 exact
__global__ __launch_bounds__(256) void beta_kernel(const float* __restrict__ x,
                                                   const float* __restrict__ Wb,
                                                   const float* __restrict__ bb,
                                                   float* __restrict__ beta) {
    __shared__ float xs[16 * 132];
    const int tid = threadIdx.x;
    const float* xr = &x[(size_t)blockIdx.x * 2048];
#pragma unroll
    for (int i = tid; i < 512; i += 256) {
        float4 v = ((const float4*)xr)[i];
        const int j = i * 4;
        *(float4*)&xs[(j >> 7) * 132 + (j & 127)] = v;
    }
    __syncthreads();
    const int n = tid >> 4, ks = tid & 15;
    const float* w  = &Wb[(size_t)n * 2048 + ks * 128];
    const float* xx = &xs[ks * 132];
    float s = 0.f;
#pragma unroll 8
    for (int j = 0; j < 128; j++) s += xx[j] * w[j];
    s += __shfl_xor(s, 1); s += __shfl_xor(s, 2);
    s += __shfl_xor(s, 4); s += __shfl_xor(s, 8);
    if (ks == 0) beta[(size_t)blockIdx.x * 16 + n] = 1.f / (1.f + __expf(-(s + bb[n])));
}

// ---------------------------------------------------------------- sequential recurrence
// R6 structure + amdgpu_waves_per_eu(1,1): max-1-wave/EU removes the backend's
// 8-wave occupancy target, so the 4-deep asm-volatile register rotation (~110 VGPR)
// allocates WITHOUT spills (R6 VGPR=56 / R7 VGPR=96 proved spilling broke the
// counted-vmcnt pipeline). 256 blocks x 4 waves = 1 wave/SIMD; grid occupancy is
// 1/SIMD anyway, so capping waves/EU costs nothing.
// Per body: wait vmcnt(24) (t's 8 loads retired, 3 sets in flight) -> sched_barrier
// -> compute t -> ISSUE t+4 into the just-consumed set. No stores in the loop:
// outputs buffered in per-wave LDS ring, flushed every 64 steps (no drain; in-wave
// LDS ordering protects the ring).
__global__ __launch_bounds__(256)
__attribute__((amdgpu_waves_per_eu(1, 1)))
void recurrence_kernel(
        const float* __restrict__ S0, const float* __restrict__ qn, const float* __restrict__ kn,
        const float* __restrict__ vv, const float* __restrict__ adec, const float* __restrict__ bet,
        const float* __restrict__ gg, __hip_bfloat16* __restrict__ o) {
    __shared__ __hip_bfloat16 lout[4][64][4];

    const int bh  = blockIdx.x & 31;   // XCD = bh % 8
    const int rb8 = blockIdx.x >> 5;   // 0..7
    const int b = bh >> 4, h = bh & 15;
    const int lane = threadIdx.x & 63;
    const int wave = threadIdx.x >> 6;
    const int r = lane >> 4;               // row within wave (0..3)
    const int c = lane & 15;               // col chunk (8 f32)
    const int i0 = rb8 * 16 + wave * 4;
    const int i = i0 + r;

    f32x4 S40, S41;
    {
        const float* s0 = &S0[((size_t)(bh * 128 + i)) * 128 + c * 8];
        S40 = *(const f32x4*)s0;
        S41 = *(const f32x4*)(s0 + 4);
    }

    const size_t hb = (size_t)(b * 2048) * 16 + h;
    const unsigned SB = 16 * 128 * 4;      // 8192 B per t-step
    const float* kbase = kn   + hb * 128;
    const float* qbase = qn   + hb * 128;
    const float* vbase = vv   + hb * 128;
    const float* abase = adec + hb * 128;
    const float* gbase = gg   + hb * 128;
    const float* bbase = bet  + hb;
    char* ob = (char*)(o + hb * 128 + i0);

    unsigned voff_kq = (unsigned)(c * 32);  // c*8 floats * 4B
    unsigned voff_i  = (unsigned)(i * 4);
    unsigned voff_b  = 0;

    f32x4 kA0, kA1, qA0, qA1; float vA, aA, gA, bA;
    f32x4 kB0, kB1, qB0, qB1; float vB, aB, gB, bB;
    f32x4 kC0, kC1, qC0, qC1; float vC, aC, gC, bC;
    f32x4 kD0, kD1, qD0, qD1; float vD, aD, gD, bD;

#define ISSUE(SET)                                                              \
    asm volatile("global_load_dwordx4 %0, %2, %3\n\t"                           \
                 "global_load_dwordx4 %1, %2, %3 offset:16"                     \
                 : "=v"(k##SET##0), "=v"(k##SET##1)                             \
                 : "v"(voff_kq), "s"(kbase));                                   \
    asm volatile("global_load_dwordx4 %0, %2, %3\n\t"                           \
                 "global_load_dwordx4 %1, %2, %3 offset:16"                     \
                 : "=v"(q##SET##0), "=v"(q##SET##1)                             \
                 : "v"(voff_kq), "s"(qbase));                                   \
    asm volatile("global_load_dword %0, %1, %2"                                 \
                 : "=v"(v##SET) : "v"(voff_i), "s"(vbase));                     \
    asm volatile("global_load_dword %0, %1, %2"                                 \
                 : "=v"(a##SET) : "v"(voff_i), "s"(abase));                     \
    asm volatile("global_load_dword %0, %1, %2"                                 \
                 : "=v"(g##SET) : "v"(voff_i), "s"(gbase));                     \
    asm volatile("global_load_dword %0, %1, %2"                                 \
                 : "=v"(b##SET) : "v"(voff_b), "s"(bbase));

#define ADV() { voff_kq += SB; voff_i += SB; voff_b += 64; }

    // prologue: issue steps 0..3 into A..D
    ISSUE(A); ADV();
    ISSUE(B); ADV();
    ISSUE(C); ADV();
    ISSUE(D); ADV();

// wait t's loads retired (24 newer outstanding), compute t from SET, buffer output
// in LDS ring, then issue L(t+4) into SET and advance.
#define BODY(SLOT, SET)                                                   \
    {                                                                     \
        asm volatile("s_waitcnt vmcnt(24)" ::: "memory");                 \
        __builtin_amdgcn_sched_barrier(0);                                \
        f32x4 ps = S40 * k##SET##0;                                       \
        ps = S41 * k##SET##1 + ps;                                        \
        float p = row_sum16((ps[0] + ps[1]) + (ps[2] + ps[3]));           \
        const float coef = b##SET * (v##SET - p);                         \
        S40 = a##SET * S40 + coef * k##SET##0;                            \
        S41 = a##SET * S41 + coef * k##SET##1;                            \
        f32x4 os = S40 * q##SET##0;                                       \
        os = S41 * q##SET##1 + os;                                        \
        float ov = row_sum16((os[0] + os[1]) + (os[2] + os[3]));          \
        if (c == 0) lout[wave][(SLOT)][r] = __float2bfloat16(ov * g##SET);\
        ISSUE(SET);                                                       \
        ADV();                                                            \
    }

    for (int tb = 0; tb < 2048; tb += 64) {
        for (int tt = 0; tt < 64; tt += 4) {
            BODY(tt,     A);
            BODY(tt + 1, B);
            BODY(tt + 2, C);
            BODY(tt + 3, D);
        }
        // flush 64 outputs: lane l -> step tb+l, 4 rows (8B). No vmcnt drain:
        // the ring WAR is ordered by in-wave LDS op ordering; the store simply
        // joins the counted vmcnt stream (waits absorb it within 3 steps).
        uint2 pk = *(const uint2*)&lout[wave][lane][0];
        *(uint2*)(ob + (size_t)(tb + lane) * 4096) = pk;
    }
#undef BODY
#undef ADV
#undef ISSUE
}

// ----------------------------------------------------------------
extern "C" void kernel_launch(void* const* d_in, const int* in_sizes, int n_in,
                              void* d_out, int out_size, void* d_ws, size_t ws_size,
                              hipStream_t stream) {
    const float* x  = (const float*)d_in[0];
    const float* S0 = (const float*)d_in[1];
    const float* Wq = (const float*)d_in[2];
    const float* Wk = (const float*)d_in[3];
    const float* Wv = (const float*)d_in[4];
    const float* Wa = (const float*)d_in[5];
    const float* ba = (const float*)d_in[6];
    const float* Wb = (const float*)d_in[7];
    const float* bb = (const float*)d_in[8];
    const float* Wg = (const float*)d_in[9];
    const float* bg = (const float*)d_in[10];
    const float* Wo = (const float*)d_in[11];
    float* out = (float*)d_out;

    const int M = 4096, N = 2048, K = 2048;
    const size_t SLACK = 8 * 16 * 128 * 4;  // 8 t-steps of prefetch slack

    size_t off = 0;
    auto alloc = [&](size_t bytes) {
        void* p = (char*)d_ws + off;
        off += (bytes + 255) & ~(size_t)255;
        return p;
    };
    short* x_bf  = (short*)alloc((size_t)M * K * 2);  // later reused as o_bf
    short* Wq_bf = (short*)alloc((size_t)N * K * 2);
    short* Wk_bf = (short*)alloc((size_t)N * K * 2);
    short* Wv_bf = (short*)alloc((size_t)N * K * 2);
    short* Wa_bf = (short*)alloc((size_t)N * K * 2);
    short* Wg_bf = (short*)alloc((size_t)N * K * 2);
    short* Wo_bf = (short*)alloc((size_t)N * K * 2);
    float* qb    = (float*)alloc((size_t)M * N * 4 + SLACK);
    float* kb    = (float*)alloc((size_t)M * N * 4 + SLACK);
    float* vb    = (float*)alloc((size_t)M * N * 4 + SLACK);
    float* ab    = (float*)alloc((size_t)M * N * 4 + SLACK);
    float* gb    = (float*)alloc((size_t)M * N * 4 + SLACK);
    float* betab = (float*)alloc((size_t)M * 16 * 4 + 32768);

    cast_bf16_kernel<<<dim3((M * K / 4 + 255) / 256), dim3(256), 0, stream>>>(x,  (__hip_bfloat16*)x_bf,  M * K);
    cast_bf16_kernel<<<dim3((N * K / 4 + 255) / 256), dim3(256), 0, stream>>>(Wq, (__hip_bfloat16*)Wq_bf, N * K);
    cast_bf16_kernel<<<dim3((N * K / 4 + 255) / 256), dim3(256), 0, stream>>>(Wk, (__hip_bfloat16*)Wk_bf, N * K);
    cast_bf16_kernel<<<dim3((N * K / 4 + 255) / 256), dim3(256), 0, stream>>>(Wv, (__hip_bfloat16*)Wv_bf, N * K);
    cast_bf16_kernel<<<dim3((N * K / 4 + 255) / 256), dim3(256), 0, stream>>>(Wa, (__hip_bfloat16*)Wa_bf, N * K);
    cast_bf16_kernel<<<dim3((N * K / 4 + 255) / 256), dim3(256), 0, stream>>>(Wg, (__hip_bfloat16*)Wg_bf, N * K);
    cast_bf16_kernel<<<dim3((N * K / 4 + 255) / 256), dim3(256), 0, stream>>>(Wo, (__hip_bfloat16*)Wo_bf, N * K);

    dim3 gdim(M / 128, N / 128), bdim(256);
    gemm_nt<0><<<gdim, bdim, 0, stream>>>(x_bf, Wq_bf, qb, nullptr, M, N, K);
    gemm_nt<0><<<gdim, bdim, 0, stream>>>(x_bf, Wk_bf, kb, nullptr, M, N, K);
    gemm_nt<0><<<gdim, bdim, 0, stream>>>(x_bf, Wv_bf, vb, nullptr, M, N, K);
    gemm_nt<1><<<gdim, bdim, 0, stream>>>(x_bf, Wa_bf, ab, ba, M, N, K);
    gemm_nt<1><<<gdim, bdim, 0, stream>>>(x_bf, Wg_bf, gb, bg, M, N, K);

    l2norm_kernel<<<dim3(M * 16 / 4), dim3(256), 0, stream>>>(qb);
    l2norm_kernel<<<dim3(M * 16 / 4), dim3(256), 0, stream>>>(kb);
    beta_kernel<<<dim3(M), dim3(256), 0, stream>>>(x, Wb, bb, betab);

    __hip_bfloat16* o_bf = (__hip_bfloat16*)x_bf;
    recurrence_kernel<<<dim3(256), dim3(256), 0, stream>>>(S0, qb, kb, vb, ab, betab, gb, o_bf);

    gemm_nt<0><<<gdim, bdim, 0, stream>>>((const short*)o_bf, Wo_bf, out, nullptr, M, N, K);
}

// Round 10
// 749.686 us; speedup vs baseline: 1.4686x; 1.0580x over previous
//
#include <hip/hip_runtime.h>
#include <hip/hip_bf16.h>

typedef short short8 __attribute__((ext_vector_type(8)));
typedef float f32x4 __attribute__((ext_vector_type(4)));

#define DEV __device__ __forceinline__
#define AS1 __attribute__((address_space(1)))
#define AS3 __attribute__((address_space(3)))

// ---------------------------------------------------------------- async 16B global->LDS (GEMM)
DEV void async_load16(const void* g, void* l) {
    __builtin_amdgcn_global_load_lds((const AS1 unsigned int*)g, (AS3 unsigned int*)l, 16, 0, 0);
}

// ---------------------------------------------------------------- DPP 16-lane sum butterfly
template <int CTRL>
DEV float dpp_add16(float v) {
    int t = __builtin_amdgcn_update_dpp(0, __float_as_int(v), CTRL, 0xf, 0xf, true);
    return v + __int_as_float(t);
}
DEV float row_sum16(float v) {
    v = dpp_add16<0x128>(v);  // row_ror:8
    v = dpp_add16<0x124>(v);  // row_ror:4
    v = dpp_add16<0x122>(v);  // row_ror:2
    v = dpp_add16<0x121>(v);  // row_ror:1
    return v;
}

// ---------------------------------------------------------------- f32 -> bf16 cast (x)
__global__ __launch_bounds__(256) void cast_bf16_kernel(const float* __restrict__ in,
                                                        __hip_bfloat16* __restrict__ out, int n) {
    int i = (blockIdx.x * 256 + threadIdx.x) * 4;
    if (i < n) {
        float4 v = *(const float4*)&in[i];
        out[i + 0] = __float2bfloat16(v.x);
        out[i + 1] = __float2bfloat16(v.y);
        out[i + 2] = __float2bfloat16(v.z);
        out[i + 3] = __float2bfloat16(v.w);
    }
}

// ---------------------------------------------------------------- 6 weight casts in one launch
// dst = contiguous [6][2048*2048] bf16; 4096 blocks per section.
__global__ __launch_bounds__(256) void cast6_kernel(const float* __restrict__ s0, const float* __restrict__ s1,
                                                    const float* __restrict__ s2, const float* __restrict__ s3,
                                                    const float* __restrict__ s4, const float* __restrict__ s5,
                                                    __hip_bfloat16* __restrict__ dst) {
    const int sec = blockIdx.x >> 12;
    const int loc = blockIdx.x & 4095;
    const float* s = sec == 0 ? s0 : sec == 1 ? s1 : sec == 2 ? s2 : sec == 3 ? s3 : sec == 4 ? s4 : s5;
    const int i = (loc * 256 + threadIdx.x) * 4;
    float4 v = *(const float4*)&s[i];
    __hip_bfloat16* o = dst + (size_t)sec * 4194304 + i;
    o[0] = __float2bfloat16(v.x);
    o[1] = __float2bfloat16(v.y);
    o[2] = __float2bfloat16(v.z);
    o[3] = __float2bfloat16(v.w);
}

// ---------------------------------------------------------------- bf16 MFMA GEMM, C = A(M,K) * B(N,K)^T
// XCD-aware swizzle (nwg divisible by 8). EPI 0: plain f32 store.
// EPI 2: fused 5-section output (q|k|v|a|g), sigmoid+bias on sections 3 (bias1) and 4 (bias2).
template <int EPI>
__global__ __launch_bounds__(256) void gemm_nt(const short* __restrict__ A,
                                               const short* __restrict__ Bm,
                                               float* __restrict__ C,
                                               const float* __restrict__ bias1,
                                               const float* __restrict__ bias2,
                                               int M, int N, int K) {
    __shared__ short lda[128 * 32];
    __shared__ short ldb[128 * 32];
    const int tid  = threadIdx.x;
    const int lane = tid & 63;
    const int wave = tid >> 6;

    const int nbx = M >> 7;  // 32
    const int wg  = blockIdx.y * gridDim.x + blockIdx.x;
    const int nwg = gridDim.x * gridDim.y;
    const int cpx = nwg >> 3;
    const int swz = (wg & 7) * cpx + (wg >> 3);
    const int m0 = (swz & (nbx - 1)) * 128;
    const int n0 = (swz / nbx) * 128;

    const int wm = (wave >> 1) * 64;
    const int wn = (wave & 1) * 64;
    f32x4 acc[4][4] = {};

    const int sr = tid >> 2;
    const int sc = (tid & 3) * 8;
    const short* Ab  = A  + (size_t)(m0 + sr) * K + sc;
    const short* Ab2 = Ab + (size_t)64 * K;
    const short* Bb  = Bm + (size_t)(n0 + sr) * K + sc;
    const short* Bb2 = Bb + (size_t)64 * K;
    short* la  = &lda[tid * 8];
    short* la2 = &lda[(tid + 256) * 8];
    short* lb  = &ldb[tid * 8];
    short* lb2 = &ldb[(tid + 256) * 8];

    const int fk = (lane >> 4) * 8;
    const int fr = lane & 15;

    for (int k0 = 0; k0 < K; k0 += 32) {
        async_load16(Ab + k0,  la);
        async_load16(Ab2 + k0, la2);
        async_load16(Bb + k0,  lb);
        async_load16(Bb2 + k0, lb2);
        __syncthreads();
        short8 af[4], bfr[4];
#pragma unroll
        for (int i = 0; i < 4; i++) af[i]  = *(const short8*)&lda[(wm + i * 16 + fr) * 32 + fk];
#pragma unroll
        for (int j = 0; j < 4; j++) bfr[j] = *(const short8*)&ldb[(wn + j * 16 + fr) * 32 + fk];
#pragma unroll
        for (int i = 0; i < 4; i++)
#pragma unroll
            for (int j = 0; j < 4; j++)
                acc[i][j] = __builtin_amdgcn_mfma_f32_16x16x32_bf16(af[i], bfr[j], acc[i][j], 0, 0, 0);
        __syncthreads();
    }

    const int er = (lane >> 4) * 4;
    const int ec = lane & 15;
    bool sig = false;
    const float* bp = nullptr;
    if constexpr (EPI == 2) {
        sig = (n0 >= 6144);
        if (sig) bp = (n0 >= 8192) ? (bias2 + (n0 - 8192)) : (bias1 + (n0 - 6144));
    }
#pragma unroll
    for (int i = 0; i < 4; i++) {
        const int gr = m0 + wm + i * 16 + er;
#pragma unroll
        for (int j = 0; j < 4; j++) {
            const int gc = n0 + wn + j * 16 + ec;
            float bia = 0.f;
            if constexpr (EPI == 2) { if (sig) bia = bp[wn + j * 16 + ec]; }
#pragma unroll
            for (int r = 0; r < 4; r++) {
                float v = acc[i][j][r];
                if constexpr (EPI == 2) { if (sig) v = 1.f / (1.f + __expf(-(v + bia))); }
                C[(size_t)(gr + r) * N + gc] = v;
            }
        }
    }
}

// ---------------------------------------------------------------- l2norm over rows of 128 (fused layout)
// Normalizes sections 0 (q) and 1 (k) of the [4096][10240] buffer.
__global__ __launch_bounds__(256) void l2norm_kernel(float* __restrict__ buf) {
    const int id   = blockIdx.x * 4 + (threadIdx.x >> 6);  // 0..131071
    const int lane = threadIdx.x & 63;
    const int t = id >> 5, rem = id & 31;
    float* p = &buf[(size_t)t * 10240 + (rem >> 4) * 2048 + (rem & 15) * 128 + lane * 2];
    float2 v = *(float2*)p;
    float s = v.x * v.x + v.y * v.y;
#pragma unroll
    for (int off = 1; off < 64; off <<= 1) s += __shfl_xor(s, off);
    const float inv = 1.f / fmaxf(sqrtf(s), 1e-12f);
    v.x *= inv; v.y *= inv;
    *(float2*)p = v;
}

// ---------------------------------------------------------------- beta = sigmoid(x @ Wb^T + bb), f32 exact
__global__ __launch_bounds__(256) void beta_kernel(const float* __restrict__ x,
                                                   const float* __restrict__ Wb,
                                                   const float* __restrict__ bb,
                                                   float* __restrict__ beta) {
    __shared__ float xs[16 * 132];
    const int tid = threadIdx.x;
    const float* xr = &x[(size_t)blockIdx.x * 2048];
#pragma unroll
    for (int i = tid; i < 512; i += 256) {
        float4 v = ((const float4*)xr)[i];
        const int j = i * 4;
        *(float4*)&xs[(j >> 7) * 132 + (j & 127)] = v;
    }
    __syncthreads();
    const int n = tid >> 4, ks = tid & 15;
    const float* w  = &Wb[(size_t)n * 2048 + ks * 128];
    const float* xx = &xs[ks * 132];
    float s = 0.f;
#pragma unroll 8
    for (int j = 0; j < 128; j++) s += xx[j] * w[j];
    s += __shfl_xor(s, 1); s += __shfl_xor(s, 2);
    s += __shfl_xor(s, 4); s += __shfl_xor(s, 8);
    if (ks == 0) beta[(size_t)blockIdx.x * 16 + n] = 1.f / (1.f + __expf(-(s + bb[n])));
}

// ---------------------------------------------------------------- sequential recurrence
// R8 structure (4-deep asm-volatile rotation, vmcnt(24), no spills at waves_per_eu(1,1))
// with the sched_barrier WALL REMOVED: a zero-cost volatile register-binding asm after the
// counted waitcnt pins consumers after the wait via dataflow, while FP ops are free to
// migrate across it -> the out-reduce tail of step t overlaps the p-dot head of step t+1.
// Streams live in the fused [4096][10240] buffer: sections q=0,k=1,v=2,a=3,g=4.
__global__ __launch_bounds__(256)
__attribute__((amdgpu_waves_per_eu(1, 1)))
void recurrence_kernel(
        const float* __restrict__ S0, const float* __restrict__ qall,
        const float* __restrict__ bet, __hip_bfloat16* __restrict__ o) {
    __shared__ __hip_bfloat16 lout[4][64][4];

    const int bh  = blockIdx.x & 31;   // XCD = bh % 8
    const int rb8 = blockIdx.x >> 5;   // 0..7
    const int b = bh >> 4, h = bh & 15;
    const int lane = threadIdx.x & 63;
    const int wave = threadIdx.x >> 6;
    const int r = lane >> 4;               // row within wave (0..3)
    const int c = lane & 15;               // col chunk (8 f32)
    const int i0 = rb8 * 16 + wave * 4;
    const int i = i0 + r;

    f32x4 S40, S41;
    {
        const float* s0 = &S0[((size_t)(bh * 128 + i)) * 128 + c * 8];
        S40 = *(const f32x4*)s0;
        S41 = *(const f32x4*)(s0 + 4);
    }

    const unsigned SB = 10240 * 4;         // bytes per t-step in fused buffer
    const float* rowb = qall + (size_t)(b * 2048) * 10240 + h * 128;
    const float* qbase = rowb;             // section 0
    const float* kbase = rowb + 2048;      // section 1
    const float* vbase = rowb + 4096;      // section 2
    const float* abase = rowb + 6144;      // section 3
    const float* gbase = rowb + 8192;      // section 4
    const float* bbase = bet + (size_t)(b * 2048) * 16 + h;
    char* ob = (char*)(o + ((size_t)(b * 2048) * 16 + h) * 128 + i0);

    unsigned voff_kq = (unsigned)(c * 32);  // c*8 floats * 4B
    unsigned voff_i  = (unsigned)(i * 4);
    unsigned voff_b  = 0;

    f32x4 kA0, kA1, qA0, qA1; float vA, aA, gA, bA;
    f32x4 kB0, kB1, qB0, qB1; float vB, aB, gB, bB;
    f32x4 kC0, kC1, qC0, qC1; float vC, aC, gC, bC;
    f32x4 kD0, kD1, qD0, qD1; float vD, aD, gD, bD;

#define ISSUE(SET)                                                              \
    asm volatile("global_load_dwordx4 %0, %2, %3\n\t"                           \
                 "global_load_dwordx4 %1, %2, %3 offset:16"                     \
                 : "=v"(k##SET##0), "=v"(k##SET##1)                             \
                 : "v"(voff_kq), "s"(kbase));                                   \
    asm volatile("global_load_dwordx4 %0, %2, %3\n\t"                           \
                 "global_load_dwordx4 %1, %2, %3 offset:16"                     \
                 : "=v"(q##SET##0), "=v"(q##SET##1)                             \
                 : "v"(voff_kq), "s"(qbase));                                   \
    asm volatile("global_load_dword %0, %1, %2"                                 \
                 : "=v"(v##SET) : "v"(voff_i), "s"(vbase));                     \
    asm volatile("global_load_dword %0, %1, %2"                                 \
                 : "=v"(a##SET) : "v"(voff_i), "s"(abase));                     \
    asm volatile("global_load_dword %0, %1, %2"                                 \
                 : "=v"(g##SET) : "v"(voff_i), "s"(gbase));                     \
    asm volatile("global_load_dword %0, %1, %2"                                 \
                 : "=v"(b##SET) : "v"(voff_b), "s"(bbase));

#define ADV() { voff_kq += SB; voff_i += SB; voff_b += 64; }

    // prologue: issue steps 0..3 into A..D
    ISSUE(A); ADV();
    ISSUE(B); ADV();
    ISSUE(C); ADV();
    ISSUE(D); ADV();

// counted wait for t's loads (24 newer outstanding), dataflow-bind the arrived set
// (no sched_barrier, no "memory" clobber -> cross-step FP overlap allowed),
// compute t, buffer output in LDS ring, issue L(t+4) into the consumed set.
#define BODY(SLOT, SET)                                                   \
    {                                                                     \
        asm volatile("s_waitcnt vmcnt(24)");                              \
        asm volatile("" : "+v"(k##SET##0), "+v"(k##SET##1),               \
                          "+v"(q##SET##0), "+v"(q##SET##1),               \
                          "+v"(v##SET), "+v"(a##SET),                     \
                          "+v"(g##SET), "+v"(b##SET));                    \
        f32x4 ps = S40 * k##SET##0;                                       \
        ps = S41 * k##SET##1 + ps;                                        \
        float p = row_sum16((ps[0] + ps[1]) + (ps[2] + ps[3]));           \
        const float coef = b##SET * (v##SET - p);                         \
        S40 = a##SET * S40 + coef * k##SET##0;                            \
        S41 = a##SET * S41 + coef * k##SET##1;                            \
        f32x4 os = S40 * q##SET##0;                                       \
        os = S41 * q##SET##1 + os;                                        \
        float ov = row_sum16((os[0] + os[1]) + (os[2] + os[3]));          \
        if (c == 0) lout[wave][(SLOT)][r] = __float2bfloat16(ov * g##SET);\
        ISSUE(SET);                                                       \
        ADV();                                                            \
    }

    for (int tb = 0; tb < 2048; tb += 64) {
        for (int tt = 0; tt < 64; tt += 4) {
            BODY(tt,     A);
            BODY(tt + 1, B);
            BODY(tt + 2, C);
            BODY(tt + 3, D);
        }
        // flush 64 outputs: lane l -> step tb+l, 4 rows (8B)
        uint2 pk = *(const uint2*)&lout[wave][lane][0];
        *(uint2*)(ob + (size_t)(tb + lane) * 4096) = pk;
    }
#undef BODY
#undef ADV
#undef ISSUE
}

// ----------------------------------------------------------------
extern "C" void kernel_launch(void* const* d_in, const int* in_sizes, int n_in,
                              void* d_out, int out_size, void* d_ws, size_t ws_size,
                              hipStream_t stream) {
    const float* x  = (const float*)d_in[0];
    const float* S0 = (const float*)d_in[1];
    const float* Wq = (const float*)d_in[2];
    const float* Wk = (const float*)d_in[3];
    const float* Wv = (const float*)d_in[4];
    const float* Wa = (const float*)d_in[5];
    const float* ba = (const float*)d_in[6];
    const float* Wb = (const float*)d_in[7];
    const float* bb = (const float*)d_in[8];
    const float* Wg = (const float*)d_in[9];
    const float* bg = (const float*)d_in[10];
    const float* Wo = (const float*)d_in[11];
    float* out = (float*)d_out;

    const int M = 4096, K = 2048;
    const int NF = 10240;                       // fused projection width
    const size_t SLACK = 8 * (size_t)NF * 4;    // prefetch overrun slack

    size_t off = 0;
    auto alloc = [&](size_t bytes) {
        void* p = (char*)d_ws + off;
        off += (bytes + 255) & ~(size_t)255;
        return p;
    };
    short* x_bf  = (short*)alloc((size_t)M * K * 2);   // later reused as o_bf
    short* W_bf  = (short*)alloc((size_t)6 * K * K * 2); // Wq|Wk|Wv|Wa|Wg|Wo contiguous
    float* qall  = (float*)alloc((size_t)M * NF * 4 + SLACK);
    float* betab = (float*)alloc((size_t)M * 16 * 4 + 32768);

    // casts
    cast_bf16_kernel<<<dim3(M * K / 1024), dim3(256), 0, stream>>>(x, (__hip_bfloat16*)x_bf, M * K);
    cast6_kernel<<<dim3(6 * 4096), dim3(256), 0, stream>>>(Wq, Wk, Wv, Wa, Wg, Wo, (__hip_bfloat16*)W_bf);

    // fused 5-projection GEMM: [4096,2048] x [10240,2048]^T -> [4096,10240]
    gemm_nt<2><<<dim3(M / 128, NF / 128), dim3(256), 0, stream>>>(
        x_bf, W_bf, qall, ba, bg, M, NF, K);

    // l2norm q,k sections; beta
    l2norm_kernel<<<dim3(32768), dim3(256), 0, stream>>>(qall);
    beta_kernel<<<dim3(M), dim3(256), 0, stream>>>(x, Wb, bb, betab);

    // recurrence: writes o (bf16) over x_bf region (dead after fused GEMM)
    __hip_bfloat16* o_bf = (__hip_bfloat16*)x_bf;
    recurrence_kernel<<<dim3(256), dim3(256), 0, stream>>>(S0, qall, betab, o_bf);

    // out = (o*g) @ Wo^T   (Wo is section 5 of W_bf)
    gemm_nt<0><<<dim3(M / 128, K / 128), dim3(256), 0, stream>>>(
        (const short*)o_bf, W_bf + (size_t)5 * K * K, out, nullptr, nullptr, M, K, K);
}